// Round 14
// baseline (135.596 us; speedup 1.0000x reference)
//
#include <hip/hip_runtime.h>
#include <math.h>

#pragma float_control(precise, on)

#define EPSF 1e-8f

// R36: knn_prep pairing (the last unoptimized kernel, ~20-25us by
// subtraction). 2 points per 512-thread block:
// - vertex loaded ONCE per thread, d2 to both points, two top-8 lists
//   (L2 traffic halved 201->100 MB; two independent insert chains = ILP);
// - extraction rounds interleave A/B butterflies (2 independent chains);
// - wave 0 merges A's 64 candidates WHILE wave 1 merges B's; tails parallel.
// Exactness: unique-packed-key top-8 is partition-independent; tail
// arithmetic verbatim => bit-identical nc/v1/dfb => identical outputs.
// ray_fin = R35 verbatim (46.5us, certified absmax 1.525879e-05).

// ---------------------------------------------------------------------------
// KNN (K=8) x 2 points + coarse normal + triangle SoA prep. 512 threads.
// ---------------------------------------------------------------------------
__global__ void __launch_bounds__(512) knn_prep_kernel(
    const float* __restrict__ x, const float* __restrict__ verts,
    const float* __restrict__ vnorm, const int* __restrict__ faces,
    float* __restrict__ tri, float* __restrict__ ncw,
    float* __restrict__ v1w, float* __restrict__ dfbw,
    int N, int V, int F) {
#pragma clang fp contract(off)
    int b = blockIdx.x;
    int tid = threadIdx.x;
    int wave = tid >> 6;
    int lane = tid & 63;
    int pA = 2 * b;
    if (pA >= N) return;
    int pB = pA + 1;
    bool hasB = pB < N;          // uniform
    int pBs = hasB ? pB : pA;

    // triangle prep (grid-strided)
    for (int gt = b * 512 + tid; gt < F; gt += gridDim.x * 512) {
        int f0 = faces[gt * 3 + 0];
        int f1 = faces[gt * 3 + 1];
        int f2 = faces[gt * 3 + 2];
        float t0x = verts[f0 * 3 + 0], t0y = verts[f0 * 3 + 1], t0z = verts[f0 * 3 + 2];
        float ax = verts[f1 * 3 + 0], ay = verts[f1 * 3 + 1], az = verts[f1 * 3 + 2];
        float bx = verts[f2 * 3 + 0], by = verts[f2 * 3 + 1], bz = verts[f2 * 3 + 2];
        float4* t4 = (float4*)(tri + (size_t)gt * 12);
        t4[0] = make_float4(t0x, t0y, t0z, ax - t0x);
        t4[1] = make_float4(ay - t0y, az - t0z, bx - t0x, by - t0y);
        t4[2] = make_float4(bz - t0z, 0.f, 0.f, 0.f);
    }

    float axx = x[pA * 3 + 0], axy = x[pA * 3 + 1], axz = x[pA * 3 + 2];
    float bxx = x[pBs * 3 + 0], bxy = x[pBs * 3 + 1], bxz = x[pBs * 3 + 2];

    unsigned long long la[8], lb[8];
#pragma unroll
    for (int i = 0; i < 8; ++i) { la[i] = ~0ULL; lb[i] = ~0ULL; }

    // shared-vertex scan: load once, insert into both points' lists
    for (int v = tid; v < V; v += 512) {
        float vx = verts[v * 3 + 0];
        float vy = verts[v * 3 + 1];
        float vz = verts[v * 3 + 2];

        float dxa = axx - vx, dya = axy - vy, dza = axz - vz;
        float d2a = ((dxa * dxa) + (dya * dya)) + (dza * dza);
        unsigned long long kA =
            (((unsigned long long)__float_as_uint(d2a)) << 32) | (unsigned int)v;
        if (kA < la[7]) {
            la[7] = kA;
#pragma unroll
            for (int j = 7; j > 0; --j) {
                if (la[j] < la[j - 1]) {
                    unsigned long long t = la[j];
                    la[j] = la[j - 1];
                    la[j - 1] = t;
                }
            }
        }

        float dxb = bxx - vx, dyb = bxy - vy, dzb = bxz - vz;
        float d2b = ((dxb * dxb) + (dyb * dyb)) + (dzb * dzb);
        unsigned long long kB =
            (((unsigned long long)__float_as_uint(d2b)) << 32) | (unsigned int)v;
        if (kB < lb[7]) {
            lb[7] = kB;
#pragma unroll
            for (int j = 7; j > 0; --j) {
                if (lb[j] < lb[j - 1]) {
                    unsigned long long t = lb[j];
                    lb[j] = lb[j - 1];
                    lb[j - 1] = t;
                }
            }
        }
    }

    // per-wave exact top-8 extraction, A/B interleaved (independent chains)
    __shared__ unsigned long long candA[64], candB[64];
#pragma unroll
    for (int j = 0; j < 8; ++j) {
        unsigned long long mA = la[0];
        unsigned long long mB = lb[0];
#pragma unroll
        for (int s = 1; s < 64; s <<= 1) {
            unsigned long long oA = __shfl_xor(mA, s, 64);
            if (oA < mA) mA = oA;
            unsigned long long oB = __shfl_xor(mB, s, 64);
            if (oB < mB) mB = oB;
        }
        if (la[0] == mA) {
#pragma unroll
            for (int t = 0; t < 7; ++t) la[t] = la[t + 1];
            la[7] = ~0ULL;
        }
        if (lb[0] == mB) {
#pragma unroll
            for (int t = 0; t < 7; ++t) lb[t] = lb[t + 1];
            lb[7] = ~0ULL;
        }
        if (lane == 0) { candA[wave * 8 + j] = mA; candB[wave * 8 + j] = mB; }
    }
    __syncthreads();

    // wave 0 merges A's 64 candidates; wave 1 merges B's — in parallel.
    if (wave > 1) return;
    if (wave == 1 && !hasB) return;

    unsigned long long c0 = (wave == 0) ? candA[lane] : candB[lane];
    unsigned long long sel[8];
#pragma unroll
    for (int j = 0; j < 8; ++j) {
        unsigned long long m = c0;
#pragma unroll
        for (int s = 1; s < 64; s <<= 1) {
            unsigned long long o = __shfl_xor(m, s, 64);
            if (o < m) m = o;
        }
        if (c0 == m) c0 = ~0ULL;
        sel[j] = m;
    }

    if (lane != 0) return;
    int p = (wave == 0) ? pA : pB;
    float xx = (wave == 0) ? axx : bxx;
    float xy = (wave == 0) ? axy : bxy;
    float xz = (wave == 0) ? axz : bxz;

    // lane-0 tail: verbatim (bit-identical arithmetic order)
    float invk[8];
    float nsx = 0.f, nsy = 0.f, nsz = 0.f;
#pragma unroll
    for (int j = 0; j < 8; ++j) {
        int id = (int)(sel[j] & 0xffffffffu);
        float d2 = __uint_as_float((unsigned int)(sel[j] >> 32));
        float inv = 1.0f / fmaxf(d2, EPSF);
        invk[j] = inv;
        nsx = nsx + vnorm[id * 3 + 0] * inv;
        nsy = nsy + vnorm[id * 3 + 1] * inv;
        nsz = nsz + vnorm[id * 3 + 2] * inv;
    }
    float Wsum = ((invk[0] + invk[1]) + (invk[2] + invk[3])) +
                 ((invk[4] + invk[5]) + (invk[6] + invk[7]));

    int id0 = (int)(sel[0] & 0xffffffffu);
    float v1x = verts[id0 * 3 + 0];
    float v1y = verts[id0 * 3 + 1];
    float v1z = verts[id0 * 3 + 2];

    float dxv = xx - v1x, dyv = xy - v1y, dzv = xz - v1z;
    float d2v1 = fmaxf(((dxv * dxv) + (dyv * dyv)) + (dzv * dzv), EPSF);
    float den = 0.01f * d2v1;
    float tdx = dxv / den, tdy = dyv / den, tdz = dzv / den;

    float W = Wsum + 100.0f;
    float ntx = (nsx + tdx) / W;
    float nty = (nsy + tdy) / W;
    float ntz = (nsz + tdz) / W;
    float nrm = sqrtf(((ntx * ntx) + (nty * nty)) + (ntz * ntz)) + 1e-8f;
    float ncx = ntx / nrm, ncy = nty / nrm, ncz = ntz / nrm;

    float fx = v1x - xx, fy = v1y - xy, fz = v1z - xz;
    float fn = sqrtf(((fx * fx) + (fy * fy)) + (fz * fz)) + 1e-8f;
    fx = fx / fn; fy = fy / fn; fz = fz / fn;

    ncw[p * 3 + 0] = ncx; ncw[p * 3 + 1] = ncy; ncw[p * 3 + 2] = ncz;
    v1w[p * 3 + 0] = v1x; v1w[p * 3 + 1] = v1y; v1w[p * 3 + 2] = v1z;
    dfbw[p * 3 + 0] = fx; dfbw[p * 3 + 1] = fy; dfbw[p * 3 + 2] = fz;
}

// ---------------------------------------------------------------------------
// One MT test, R30-verbatim op order, contract off inside (R34-certified).
// ---------------------------------------------------------------------------
__device__ __forceinline__ float mt_test(
    float ox, float oy, float oz, float dx, float dy, float dz,
    const float4 A, const float4 B, const float4 C, float tb) {
#pragma clang fp contract(off)
    const float M = 1e-5f;  // graze margin (R21-certified)
    float e1x = A.w, e1y = B.x, e1z = B.y;
    float e2x = B.z, e2y = B.w, e2z = C.x;
    float tvx = ox - A.x;
    float tvy = oy - A.y;
    float tvz = oz - A.z;
    float qx = (tvy * e1z) - (tvz * e1y);
    float qy = (tvz * e1x) - (tvx * e1z);
    float qz = (tvx * e1y) - (tvy * e1x);
    float tq = ((e2x * qx) + (e2y * qy)) + (e2z * qz);
    float px = (dy * e2z) - (dz * e2y);
    float py = (dz * e2x) - (dx * e2z);
    float pz = (dx * e2y) - (dy * e2x);
    float det = ((e1x * px) + (e1y * py)) + (e1z * pz);
    bool ok = fabsf(det) > EPSF;
    float inv = ok ? (1.0f / det) : 0.0f;
    float u = (((tvx * px) + (tvy * py)) + (tvz * pz)) * inv;
    float v = (((dx * qx) + (dy * qy)) + (dz * qz)) * inv;
    float t = tq * inv;
    bool valid = ok && (u >= -M) && (v >= -M) && ((u + v) <= 1.0f + M) && (t > EPSF);
    return (valid && t < tb) ? t : tb;
}

// ---------------------------------------------------------------------------
// ray + reduce + finalize: R35 verbatim. 512 threads, block = 2 points.
// ---------------------------------------------------------------------------
__global__ void __launch_bounds__(512) ray_fin_kernel(
    const float* __restrict__ x, const float* __restrict__ tri,
    const float* __restrict__ ncw, const float* __restrict__ v1w,
    const float* __restrict__ dfbw, float* __restrict__ out, int N, int F) {
#pragma clang fp contract(off)
    __shared__ unsigned int redA[8], redB[8];
    __shared__ unsigned int u1As, u1Bs, u2As, u2Bs, hAf, hBf;
    int b = blockIdx.x;
    int tid = threadIdx.x;
    int wave = tid >> 6;
    int lane = tid & 63;
    int pA = 2 * b;
    if (pA >= N) return;
    int pB = pA + 1;
    bool hasB = pB < N;      // uniform
    int pBs = hasB ? pB : pA;

    float axx = x[pA * 3 + 0], axy = x[pA * 3 + 1], axz = x[pA * 3 + 2];
    float Ancx = ncw[pA * 3 + 0], Ancy = ncw[pA * 3 + 1], Ancz = ncw[pA * 3 + 2];
    float Adbx = dfbw[pA * 3 + 0], Adby = dfbw[pA * 3 + 1], Adbz = dfbw[pA * 3 + 2];
    float Adax = -Ancx, Aday = -Ancy, Adaz = -Ancz;

    float bxx = x[pBs * 3 + 0], bxy = x[pBs * 3 + 1], bxz = x[pBs * 3 + 2];
    float Bncx = ncw[pBs * 3 + 0], Bncy = ncw[pBs * 3 + 1], Bncz = ncw[pBs * 3 + 2];
    float Bdbx = dfbw[pBs * 3 + 0], Bdby = dfbw[pBs * 3 + 1], Bdbz = dfbw[pBs * 3 + 2];
    float Bdax = -Bncx, Bday = -Bncy, Bdaz = -Bncz;

    const float INF = __uint_as_float(0x7f800000u);

    // -------- pass A: both points' primary rays (-nc), tri loaded once ----
    float tA = INF, tB = INF;
    for (int fi = tid; fi < F; fi += 512) {
        const float4 A4 = *(const float4*)(tri + (size_t)fi * 12);
        const float4 B4 = *(const float4*)(tri + (size_t)fi * 12 + 4);
        const float4 C4 = *(const float4*)(tri + (size_t)fi * 12 + 8);
        tA = mt_test(axx, axy, axz, Adax, Aday, Adaz, A4, B4, C4, tA);
        tB = mt_test(bxx, bxy, bxz, Bdax, Bday, Bdaz, A4, B4, C4, tB);
    }

    {
        unsigned int ma = __float_as_uint(tA);
        unsigned int mb = __float_as_uint(tB);
#pragma unroll
        for (int s = 1; s < 64; s <<= 1) {
            unsigned int oa = __shfl_xor(ma, s, 64);
            if (oa < ma) ma = oa;
            unsigned int ob = __shfl_xor(mb, s, 64);
            if (ob < mb) mb = ob;
        }
        if (lane == 0) { redA[wave] = ma; redB[wave] = mb; }
    }
    __syncthreads();
    if (tid == 0) {
        unsigned int u1A = min(min(min(redA[0], redA[1]), min(redA[2], redA[3])),
                               min(min(redA[4], redA[5]), min(redA[6], redA[7])));
        unsigned int u1B = min(min(min(redB[0], redB[1]), min(redB[2], redB[3])),
                               min(min(redB[4], redB[5]), min(redB[6], redB[7])));
        u1As = u1A; u1Bs = u1B;
        hAf = (u1A < 0x7f800000u) ? 1u : 0u;
        hBf = (u1B < 0x7f800000u) ? 1u : 0u;
    }
    __syncthreads();

    // -------- pass B: fallback rays (dfb), per-point-guarded --------------
    bool needA = (hAf == 0u);                 // block-uniform
    bool needB = hasB && (hBf == 0u);         // block-uniform
    if (needA || needB) {
        float sA = INF, sB = INF;
        for (int fi = tid; fi < F; fi += 512) {
            const float4 A4 = *(const float4*)(tri + (size_t)fi * 12);
            const float4 B4 = *(const float4*)(tri + (size_t)fi * 12 + 4);
            const float4 C4 = *(const float4*)(tri + (size_t)fi * 12 + 8);
            if (needA) sA = mt_test(axx, axy, axz, Adbx, Adby, Adbz, A4, B4, C4, sA);
            if (needB) sB = mt_test(bxx, bxy, bxz, Bdbx, Bdby, Bdbz, A4, B4, C4, sB);
        }
        unsigned int ma = __float_as_uint(sA);
        unsigned int mb = __float_as_uint(sB);
#pragma unroll
        for (int s = 1; s < 64; s <<= 1) {
            unsigned int oa = __shfl_xor(ma, s, 64);
            if (oa < ma) ma = oa;
            unsigned int ob = __shfl_xor(mb, s, 64);
            if (ob < mb) mb = ob;
        }
        if (lane == 0) { redA[wave] = ma; redB[wave] = mb; }
        __syncthreads();
        if (tid == 0) {
            u2As = min(min(min(redA[0], redA[1]), min(redA[2], redA[3])),
                       min(min(redA[4], redA[5]), min(redA[6], redA[7])));
            u2Bs = min(min(min(redB[0], redB[1]), min(redB[2], redB[3])),
                       min(min(redB[4], redB[5]), min(redB[6], redB[7])));
        }
    }

    // -------- finalize (verbatim per point), thread 0 ---------------------
    if (tid != 0) return;
    {
        float t1 = __uint_as_float(u1As);
        bool h1 = t1 < INF;
        float t2 = h1 ? INF : __uint_as_float(u2As);
        bool h2 = t2 < INF;
        float xcx, xcy, xcz;
        if (h1) {
            xcx = axx + ((-Ancx) * t1);
            xcy = axy + ((-Ancy) * t1);
            xcz = axz + ((-Ancz) * t1);
        } else if (h2) {
            xcx = axx + (Adbx * t2);
            xcy = axy + (Adby * t2);
            xcz = axz + (Adbz * t2);
        } else {
            xcx = v1w[pA * 3 + 0]; xcy = v1w[pA * 3 + 1]; xcz = v1w[pA * 3 + 2];
        }
        float s = (((axx - xcx) * Ancx) + ((axy - xcy) * Ancy)) + ((axz - xcz) * Ancz);
        out[pA * 3 + 0] = xcx;
        out[pA * 3 + 1] = xcy;
        out[pA * 3 + 2] = xcz;
        out[3 * N + pA] = s;
        out[4 * N + pA * 3 + 0] = Ancx;
        out[4 * N + pA * 3 + 1] = Ancy;
        out[4 * N + pA * 3 + 2] = Ancz;
    }
    if (hasB) {
        float t1 = __uint_as_float(u1Bs);
        bool h1 = t1 < INF;
        float t2 = h1 ? INF : __uint_as_float(u2Bs);
        bool h2 = t2 < INF;
        float xcx, xcy, xcz;
        if (h1) {
            xcx = bxx + ((-Bncx) * t1);
            xcy = bxy + ((-Bncy) * t1);
            xcz = bxz + ((-Bncz) * t1);
        } else if (h2) {
            xcx = bxx + (Bdbx * t2);
            xcy = bxy + (Bdby * t2);
            xcz = bxz + (Bdbz * t2);
        } else {
            xcx = v1w[pB * 3 + 0]; xcy = v1w[pB * 3 + 1]; xcz = v1w[pB * 3 + 2];
        }
        float s = (((bxx - xcx) * Bncx) + ((bxy - xcy) * Bncy)) + ((bxz - xcz) * Bncz);
        out[pB * 3 + 0] = xcx;
        out[pB * 3 + 1] = xcy;
        out[pB * 3 + 2] = xcz;
        out[3 * N + pB] = s;
        out[4 * N + pB * 3 + 0] = Bncx;
        out[4 * N + pB * 3 + 1] = Bncy;
        out[4 * N + pB * 3 + 2] = Bncz;
    }
}

// ---------------------------------------------------------------------------
extern "C" void kernel_launch(void* const* d_in, const int* in_sizes, int n_in,
                              void* d_out, int out_size, void* d_ws, size_t ws_size,
                              hipStream_t stream) {
    const float* x     = (const float*)d_in[0];
    const float* verts = (const float*)d_in[1];
    const float* vnorm = (const float*)d_in[2];
    const int*   faces = (const int*)d_in[3];
    int N = in_sizes[0] / 3;
    int V = in_sizes[1] / 3;
    int F = in_sizes[3] / 3;

    float* tri  = (float*)d_ws;          // F*12 floats (16B-aligned AoS)
    float* ncw  = tri + (size_t)F * 12;  // 3*N
    float* v1w  = ncw + 3 * N;           // 3*N
    float* dfbw = v1w + 3 * N;           // 3*N

    int pblocks = (N + 1) / 2;
    hipLaunchKernelGGL(knn_prep_kernel, dim3(pblocks), dim3(512), 0, stream,
                       x, verts, vnorm, faces, tri, ncw, v1w, dfbw, N, V, F);
    hipLaunchKernelGGL(ray_fin_kernel, dim3(pblocks), dim3(512), 0, stream,
                       x, tri, ncw, v1w, dfbw, (float*)d_out, N, F);
}

// Round 15
// 133.016 us; speedup vs baseline: 1.0194x; 1.0194x over previous
//
#include <hip/hip_runtime.h>
#include <math.h>

#pragma float_control(precise, on)

#define EPSF 1e-8f

// R37: phase-mixing fusion. knn(50us, VALU-gap-bound) and ray(46us,
// L2-latency-bound) each idle ~45% — fused into ONE kernel so staggered
// blocks overlap the two profiles on each CU. tri prep moved to its own
// tiny dispatch (16 blocks, ~3us) so no cross-block dependency exists in
// the fused kernel (R29/R31 sync poison avoided by construction).
// nc/v1/dfb pass through LDS (no global round-trip). All phases are the
// certified code verbatim: R36 scan/extract/merge/tail, R34 mt_test,
// R35 ray/finalize => absmax 1.525879e-05 unchanged.

// ---------------------------------------------------------------------------
// tri prep: thread = triangle (verbatim staging expressions).
// ---------------------------------------------------------------------------
__global__ void __launch_bounds__(512) tri_prep_kernel(
    const float* __restrict__ verts, const int* __restrict__ faces,
    float* __restrict__ tri, int F) {
#pragma clang fp contract(off)
    int gt = blockIdx.x * 512 + threadIdx.x;
    if (gt >= F) return;
    int f0 = faces[gt * 3 + 0];
    int f1 = faces[gt * 3 + 1];
    int f2 = faces[gt * 3 + 2];
    float t0x = verts[f0 * 3 + 0], t0y = verts[f0 * 3 + 1], t0z = verts[f0 * 3 + 2];
    float ax = verts[f1 * 3 + 0], ay = verts[f1 * 3 + 1], az = verts[f1 * 3 + 2];
    float bx = verts[f2 * 3 + 0], by = verts[f2 * 3 + 1], bz = verts[f2 * 3 + 2];
    float4* t4 = (float4*)(tri + (size_t)gt * 12);
    t4[0] = make_float4(t0x, t0y, t0z, ax - t0x);
    t4[1] = make_float4(ay - t0y, az - t0z, bx - t0x, by - t0y);
    t4[2] = make_float4(bz - t0z, 0.f, 0.f, 0.f);
}

// ---------------------------------------------------------------------------
// One MT test, R30-verbatim op order, contract off inside (R34-certified).
// ---------------------------------------------------------------------------
__device__ __forceinline__ float mt_test(
    float ox, float oy, float oz, float dx, float dy, float dz,
    const float4 A, const float4 B, const float4 C, float tb) {
#pragma clang fp contract(off)
    const float M = 1e-5f;  // graze margin (R21-certified)
    float e1x = A.w, e1y = B.x, e1z = B.y;
    float e2x = B.z, e2y = B.w, e2z = C.x;
    float tvx = ox - A.x;
    float tvy = oy - A.y;
    float tvz = oz - A.z;
    float qx = (tvy * e1z) - (tvz * e1y);
    float qy = (tvz * e1x) - (tvx * e1z);
    float qz = (tvx * e1y) - (tvy * e1x);
    float tq = ((e2x * qx) + (e2y * qy)) + (e2z * qz);
    float px = (dy * e2z) - (dz * e2y);
    float py = (dz * e2x) - (dx * e2z);
    float pz = (dx * e2y) - (dy * e2x);
    float det = ((e1x * px) + (e1y * py)) + (e1z * pz);
    bool ok = fabsf(det) > EPSF;
    float inv = ok ? (1.0f / det) : 0.0f;
    float u = (((tvx * px) + (tvy * py)) + (tvz * pz)) * inv;
    float v = (((dx * qx) + (dy * qy)) + (dz * qz)) * inv;
    float t = tq * inv;
    bool valid = ok && (u >= -M) && (v >= -M) && ((u + v) <= 1.0f + M) && (t > EPSF);
    return (valid && t < tb) ? t : tb;
}

// ---------------------------------------------------------------------------
// Fused knn + ray + finalize: 512 threads, block = 2 points {2b, 2b+1}.
// ---------------------------------------------------------------------------
__global__ void __launch_bounds__(512) fused_kernel(
    const float* __restrict__ x, const float* __restrict__ verts,
    const float* __restrict__ vnorm, const float* __restrict__ tri,
    float* __restrict__ out, int N, int V, int F) {
#pragma clang fp contract(off)
    __shared__ unsigned long long candA[64], candB[64];
    __shared__ float bcA[9], bcB[9];   // nc[0..2], v1[3..5], dfb[6..8]
    __shared__ unsigned int redA[8], redB[8];
    __shared__ unsigned int u1As, u1Bs, u2As, u2Bs, hAf, hBf;

    int b = blockIdx.x;
    int tid = threadIdx.x;
    int wave = tid >> 6;
    int lane = tid & 63;
    int pA = 2 * b;
    if (pA >= N) return;           // uniform (grid = ceil(N/2))
    int pB = pA + 1;
    bool hasB = pB < N;            // uniform
    int pBs = hasB ? pB : pA;

    float axx = x[pA * 3 + 0], axy = x[pA * 3 + 1], axz = x[pA * 3 + 2];
    float bxx = x[pBs * 3 + 0], bxy = x[pBs * 3 + 1], bxz = x[pBs * 3 + 2];

    // ---------------- phase 1: paired KNN scan (R36 verbatim) -------------
    unsigned long long la[8], lb[8];
#pragma unroll
    for (int i = 0; i < 8; ++i) { la[i] = ~0ULL; lb[i] = ~0ULL; }

    for (int v = tid; v < V; v += 512) {
        float vx = verts[v * 3 + 0];
        float vy = verts[v * 3 + 1];
        float vz = verts[v * 3 + 2];

        float dxa = axx - vx, dya = axy - vy, dza = axz - vz;
        float d2a = ((dxa * dxa) + (dya * dya)) + (dza * dza);
        unsigned long long kA =
            (((unsigned long long)__float_as_uint(d2a)) << 32) | (unsigned int)v;
        if (kA < la[7]) {
            la[7] = kA;
#pragma unroll
            for (int j = 7; j > 0; --j) {
                if (la[j] < la[j - 1]) {
                    unsigned long long t = la[j];
                    la[j] = la[j - 1];
                    la[j - 1] = t;
                }
            }
        }

        float dxb = bxx - vx, dyb = bxy - vy, dzb = bxz - vz;
        float d2b = ((dxb * dxb) + (dyb * dyb)) + (dzb * dzb);
        unsigned long long kB =
            (((unsigned long long)__float_as_uint(d2b)) << 32) | (unsigned int)v;
        if (kB < lb[7]) {
            lb[7] = kB;
#pragma unroll
            for (int j = 7; j > 0; --j) {
                if (lb[j] < lb[j - 1]) {
                    unsigned long long t = lb[j];
                    lb[j] = lb[j - 1];
                    lb[j - 1] = t;
                }
            }
        }
    }

    // per-wave exact top-8 extraction, A/B interleaved (R36 verbatim)
#pragma unroll
    for (int j = 0; j < 8; ++j) {
        unsigned long long mA = la[0];
        unsigned long long mB = lb[0];
#pragma unroll
        for (int s = 1; s < 64; s <<= 1) {
            unsigned long long oA = __shfl_xor(mA, s, 64);
            if (oA < mA) mA = oA;
            unsigned long long oB = __shfl_xor(mB, s, 64);
            if (oB < mB) mB = oB;
        }
        if (la[0] == mA) {
#pragma unroll
            for (int t = 0; t < 7; ++t) la[t] = la[t + 1];
            la[7] = ~0ULL;
        }
        if (lb[0] == mB) {
#pragma unroll
            for (int t = 0; t < 7; ++t) lb[t] = lb[t + 1];
            lb[7] = ~0ULL;
        }
        if (lane == 0) { candA[wave * 8 + j] = mA; candB[wave * 8 + j] = mB; }
    }
    __syncthreads();

    // wave 0 merges A, wave 1 merges B (parallel); results to LDS bc arrays
    if (wave < 2) {
        unsigned long long c0 = (wave == 0) ? candA[lane] : candB[lane];
        unsigned long long sel[8];
#pragma unroll
        for (int j = 0; j < 8; ++j) {
            unsigned long long m = c0;
#pragma unroll
            for (int s = 1; s < 64; s <<= 1) {
                unsigned long long o = __shfl_xor(m, s, 64);
                if (o < m) m = o;
            }
            if (c0 == m) c0 = ~0ULL;
            sel[j] = m;
        }

        if (lane == 0) {
            float xx = (wave == 0) ? axx : bxx;
            float xy = (wave == 0) ? axy : bxy;
            float xz = (wave == 0) ? axz : bxz;

            // lane-0 tail: verbatim (bit-identical arithmetic order)
            float invk[8];
            float nsx = 0.f, nsy = 0.f, nsz = 0.f;
#pragma unroll
            for (int j = 0; j < 8; ++j) {
                int id = (int)(sel[j] & 0xffffffffu);
                float d2 = __uint_as_float((unsigned int)(sel[j] >> 32));
                float inv = 1.0f / fmaxf(d2, EPSF);
                invk[j] = inv;
                nsx = nsx + vnorm[id * 3 + 0] * inv;
                nsy = nsy + vnorm[id * 3 + 1] * inv;
                nsz = nsz + vnorm[id * 3 + 2] * inv;
            }
            float Wsum = ((invk[0] + invk[1]) + (invk[2] + invk[3])) +
                         ((invk[4] + invk[5]) + (invk[6] + invk[7]));

            int id0 = (int)(sel[0] & 0xffffffffu);
            float v1x = verts[id0 * 3 + 0];
            float v1y = verts[id0 * 3 + 1];
            float v1z = verts[id0 * 3 + 2];

            float dxv = xx - v1x, dyv = xy - v1y, dzv = xz - v1z;
            float d2v1 = fmaxf(((dxv * dxv) + (dyv * dyv)) + (dzv * dzv), EPSF);
            float den = 0.01f * d2v1;
            float tdx = dxv / den, tdy = dyv / den, tdz = dzv / den;

            float W = Wsum + 100.0f;
            float ntx = (nsx + tdx) / W;
            float nty = (nsy + tdy) / W;
            float ntz = (nsz + tdz) / W;
            float nrm = sqrtf(((ntx * ntx) + (nty * nty)) + (ntz * ntz)) + 1e-8f;

            float fx = v1x - xx, fy = v1y - xy, fz = v1z - xz;
            float fn = sqrtf(((fx * fx) + (fy * fy)) + (fz * fz)) + 1e-8f;

            float* bc = (wave == 0) ? bcA : bcB;
            bc[0] = ntx / nrm; bc[1] = nty / nrm; bc[2] = ntz / nrm;
            bc[3] = v1x; bc[4] = v1y; bc[5] = v1z;
            bc[6] = fx / fn; bc[7] = fy / fn; bc[8] = fz / fn;
        }
    }
    __syncthreads();

    // ---------------- phase 2: ray (R35 verbatim, sources from LDS) -------
    float Ancx = bcA[0], Ancy = bcA[1], Ancz = bcA[2];
    float Adbx = bcA[6], Adby = bcA[7], Adbz = bcA[8];
    float Adax = -Ancx, Aday = -Ancy, Adaz = -Ancz;
    float Bncx = bcB[0], Bncy = bcB[1], Bncz = bcB[2];
    float Bdbx = bcB[6], Bdby = bcB[7], Bdbz = bcB[8];
    float Bdax = -Bncx, Bday = -Bncy, Bdaz = -Bncz;

    const float INF = __uint_as_float(0x7f800000u);

    float tA = INF, tB = INF;
    for (int fi = tid; fi < F; fi += 512) {
        const float4 A4 = *(const float4*)(tri + (size_t)fi * 12);
        const float4 B4 = *(const float4*)(tri + (size_t)fi * 12 + 4);
        const float4 C4 = *(const float4*)(tri + (size_t)fi * 12 + 8);
        tA = mt_test(axx, axy, axz, Adax, Aday, Adaz, A4, B4, C4, tA);
        tB = mt_test(bxx, bxy, bxz, Bdax, Bday, Bdaz, A4, B4, C4, tB);
    }

    {
        unsigned int ma = __float_as_uint(tA);
        unsigned int mb = __float_as_uint(tB);
#pragma unroll
        for (int s = 1; s < 64; s <<= 1) {
            unsigned int oa = __shfl_xor(ma, s, 64);
            if (oa < ma) ma = oa;
            unsigned int ob = __shfl_xor(mb, s, 64);
            if (ob < mb) mb = ob;
        }
        if (lane == 0) { redA[wave] = ma; redB[wave] = mb; }
    }
    __syncthreads();
    if (tid == 0) {
        unsigned int u1A = min(min(min(redA[0], redA[1]), min(redA[2], redA[3])),
                               min(min(redA[4], redA[5]), min(redA[6], redA[7])));
        unsigned int u1B = min(min(min(redB[0], redB[1]), min(redB[2], redB[3])),
                               min(min(redB[4], redB[5]), min(redB[6], redB[7])));
        u1As = u1A; u1Bs = u1B;
        hAf = (u1A < 0x7f800000u) ? 1u : 0u;
        hBf = (u1B < 0x7f800000u) ? 1u : 0u;
    }
    __syncthreads();

    bool needA = (hAf == 0u);                 // block-uniform
    bool needB = hasB && (hBf == 0u);         // block-uniform
    if (needA || needB) {
        float sA = INF, sB = INF;
        for (int fi = tid; fi < F; fi += 512) {
            const float4 A4 = *(const float4*)(tri + (size_t)fi * 12);
            const float4 B4 = *(const float4*)(tri + (size_t)fi * 12 + 4);
            const float4 C4 = *(const float4*)(tri + (size_t)fi * 12 + 8);
            if (needA) sA = mt_test(axx, axy, axz, Adbx, Adby, Adbz, A4, B4, C4, sA);
            if (needB) sB = mt_test(bxx, bxy, bxz, Bdbx, Bdby, Bdbz, A4, B4, C4, sB);
        }
        unsigned int ma = __float_as_uint(sA);
        unsigned int mb = __float_as_uint(sB);
#pragma unroll
        for (int s = 1; s < 64; s <<= 1) {
            unsigned int oa = __shfl_xor(ma, s, 64);
            if (oa < ma) ma = oa;
            unsigned int ob = __shfl_xor(mb, s, 64);
            if (ob < mb) mb = ob;
        }
        if (lane == 0) { redA[wave] = ma; redB[wave] = mb; }
        __syncthreads();
        if (tid == 0) {
            u2As = min(min(min(redA[0], redA[1]), min(redA[2], redA[3])),
                       min(min(redA[4], redA[5]), min(redA[6], redA[7])));
            u2Bs = min(min(min(redB[0], redB[1]), min(redB[2], redB[3])),
                       min(min(redB[4], redB[5]), min(redB[6], redB[7])));
        }
    }

    // ---------------- finalize (verbatim per point), thread 0 -------------
    if (tid != 0) return;
    {
        float t1 = __uint_as_float(u1As);
        bool h1 = t1 < INF;
        float t2 = h1 ? INF : __uint_as_float(u2As);
        bool h2 = t2 < INF;
        float xcx, xcy, xcz;
        if (h1) {
            xcx = axx + ((-Ancx) * t1);
            xcy = axy + ((-Ancy) * t1);
            xcz = axz + ((-Ancz) * t1);
        } else if (h2) {
            xcx = axx + (Adbx * t2);
            xcy = axy + (Adby * t2);
            xcz = axz + (Adbz * t2);
        } else {
            xcx = bcA[3]; xcy = bcA[4]; xcz = bcA[5];
        }
        float s = (((axx - xcx) * Ancx) + ((axy - xcy) * Ancy)) + ((axz - xcz) * Ancz);
        out[pA * 3 + 0] = xcx;
        out[pA * 3 + 1] = xcy;
        out[pA * 3 + 2] = xcz;
        out[3 * N + pA] = s;
        out[4 * N + pA * 3 + 0] = Ancx;
        out[4 * N + pA * 3 + 1] = Ancy;
        out[4 * N + pA * 3 + 2] = Ancz;
    }
    if (hasB) {
        float t1 = __uint_as_float(u1Bs);
        bool h1 = t1 < INF;
        float t2 = h1 ? INF : __uint_as_float(u2Bs);
        bool h2 = t2 < INF;
        float xcx, xcy, xcz;
        if (h1) {
            xcx = bxx + ((-Bncx) * t1);
            xcy = bxy + ((-Bncy) * t1);
            xcz = bxz + ((-Bncz) * t1);
        } else if (h2) {
            xcx = bxx + (Bdbx * t2);
            xcy = bxy + (Bdby * t2);
            xcz = bxz + (Bdbz * t2);
        } else {
            xcx = bcB[3]; xcy = bcB[4]; xcz = bcB[5];
        }
        float s = (((bxx - xcx) * Bncx) + ((bxy - xcy) * Bncy)) + ((bxz - xcz) * Bncz);
        out[pB * 3 + 0] = xcx;
        out[pB * 3 + 1] = xcy;
        out[pB * 3 + 2] = xcz;
        out[4 * N + pB * 3 + 0] = Bncx;
        out[4 * N + pB * 3 + 1] = Bncy;
        out[4 * N + pB * 3 + 2] = Bncz;
        out[3 * N + pB] = s;
    }
}

// ---------------------------------------------------------------------------
extern "C" void kernel_launch(void* const* d_in, const int* in_sizes, int n_in,
                              void* d_out, int out_size, void* d_ws, size_t ws_size,
                              hipStream_t stream) {
    const float* x     = (const float*)d_in[0];
    const float* verts = (const float*)d_in[1];
    const float* vnorm = (const float*)d_in[2];
    const int*   faces = (const int*)d_in[3];
    int N = in_sizes[0] / 3;
    int V = in_sizes[1] / 3;
    int F = in_sizes[3] / 3;

    float* tri = (float*)d_ws;   // F*12 floats (16B-aligned AoS)

    int tblocks = (F + 511) / 512;
    hipLaunchKernelGGL(tri_prep_kernel, dim3(tblocks), dim3(512), 0, stream,
                       verts, faces, tri, F);
    int pblocks = (N + 1) / 2;
    hipLaunchKernelGGL(fused_kernel, dim3(pblocks), dim3(512), 0, stream,
                       x, verts, vnorm, tri, (float*)d_out, N, V, F);
}

// Round 16
// 130.659 us; speedup vs baseline: 1.0378x; 1.0180x over previous
//
#include <hip/hip_runtime.h>
#include <math.h>

#pragma float_control(precise, on)

#define EPSF 1e-8f

// R38: knn fill+sort-network. Per-thread top-8 over only 16 candidates means
// ~13/16 iterations took the serial 7-step 64-bit insert chain (inserts
// outweigh d2 math ~3:1). Now: first 8 candidates stored UNCONDITIONALLY
// (8 independent d2 chains, no compares; ~0ULL sentinels guard V<4096),
// then ONE Batcher 8-sort network (19 comparators, depth 6, A/B lists
// interleaved), then the remaining iterations use the verbatim conditional
// sorted-insert. Same candidate set + same d2 bits + unique keys => same
// sorted list state => bit-identical outputs. Ray/finalize/tri_prep = R37.

// ---------------------------------------------------------------------------
// tri prep: thread = triangle (verbatim staging expressions).
// ---------------------------------------------------------------------------
__global__ void __launch_bounds__(512) tri_prep_kernel(
    const float* __restrict__ verts, const int* __restrict__ faces,
    float* __restrict__ tri, int F) {
#pragma clang fp contract(off)
    int gt = blockIdx.x * 512 + threadIdx.x;
    if (gt >= F) return;
    int f0 = faces[gt * 3 + 0];
    int f1 = faces[gt * 3 + 1];
    int f2 = faces[gt * 3 + 2];
    float t0x = verts[f0 * 3 + 0], t0y = verts[f0 * 3 + 1], t0z = verts[f0 * 3 + 2];
    float ax = verts[f1 * 3 + 0], ay = verts[f1 * 3 + 1], az = verts[f1 * 3 + 2];
    float bx = verts[f2 * 3 + 0], by = verts[f2 * 3 + 1], bz = verts[f2 * 3 + 2];
    float4* t4 = (float4*)(tri + (size_t)gt * 12);
    t4[0] = make_float4(t0x, t0y, t0z, ax - t0x);
    t4[1] = make_float4(ay - t0y, az - t0z, bx - t0x, by - t0y);
    t4[2] = make_float4(bz - t0z, 0.f, 0.f, 0.f);
}

// ---------------------------------------------------------------------------
// One MT test, R30-verbatim op order, contract off inside (R34-certified).
// ---------------------------------------------------------------------------
__device__ __forceinline__ float mt_test(
    float ox, float oy, float oz, float dx, float dy, float dz,
    const float4 A, const float4 B, const float4 C, float tb) {
#pragma clang fp contract(off)
    const float M = 1e-5f;  // graze margin (R21-certified)
    float e1x = A.w, e1y = B.x, e1z = B.y;
    float e2x = B.z, e2y = B.w, e2z = C.x;
    float tvx = ox - A.x;
    float tvy = oy - A.y;
    float tvz = oz - A.z;
    float qx = (tvy * e1z) - (tvz * e1y);
    float qy = (tvz * e1x) - (tvx * e1z);
    float qz = (tvx * e1y) - (tvy * e1x);
    float tq = ((e2x * qx) + (e2y * qy)) + (e2z * qz);
    float px = (dy * e2z) - (dz * e2y);
    float py = (dz * e2x) - (dx * e2z);
    float pz = (dx * e2y) - (dy * e2x);
    float det = ((e1x * px) + (e1y * py)) + (e1z * pz);
    bool ok = fabsf(det) > EPSF;
    float inv = ok ? (1.0f / det) : 0.0f;
    float u = (((tvx * px) + (tvy * py)) + (tvz * pz)) * inv;
    float v = (((dx * qx) + (dy * qy)) + (dz * qz)) * inv;
    float t = tq * inv;
    bool valid = ok && (u >= -M) && (v >= -M) && ((u + v) <= 1.0f + M) && (t > EPSF);
    return (valid && t < tb) ? t : tb;
}

// ---------------------------------------------------------------------------
// Fused knn + ray + finalize: 512 threads, block = 2 points {2b, 2b+1}.
// ---------------------------------------------------------------------------
__global__ void __launch_bounds__(512) fused_kernel(
    const float* __restrict__ x, const float* __restrict__ verts,
    const float* __restrict__ vnorm, const float* __restrict__ tri,
    float* __restrict__ out, int N, int V, int F) {
#pragma clang fp contract(off)
    __shared__ unsigned long long candA[64], candB[64];
    __shared__ float bcA[9], bcB[9];   // nc[0..2], v1[3..5], dfb[6..8]
    __shared__ unsigned int redA[8], redB[8];
    __shared__ unsigned int u1As, u1Bs, u2As, u2Bs, hAf, hBf;

    int b = blockIdx.x;
    int tid = threadIdx.x;
    int wave = tid >> 6;
    int lane = tid & 63;
    int pA = 2 * b;
    if (pA >= N) return;           // uniform (grid = ceil(N/2))
    int pB = pA + 1;
    bool hasB = pB < N;            // uniform
    int pBs = hasB ? pB : pA;

    float axx = x[pA * 3 + 0], axy = x[pA * 3 + 1], axz = x[pA * 3 + 2];
    float bxx = x[pBs * 3 + 0], bxy = x[pBs * 3 + 1], bxz = x[pBs * 3 + 2];

    // ---------------- phase 1a: unconditional fill of first 8 candidates --
    unsigned long long la[8], lb[8];
#pragma unroll
    for (int i = 0; i < 8; ++i) {
        int v = tid + i * 512;
        unsigned long long kA = ~0ULL, kB = ~0ULL;
        if (v < V) {
            float vx = verts[v * 3 + 0];
            float vy = verts[v * 3 + 1];
            float vz = verts[v * 3 + 2];
            float dxa = axx - vx, dya = axy - vy, dza = axz - vz;
            float d2a = ((dxa * dxa) + (dya * dya)) + (dza * dza);
            kA = (((unsigned long long)__float_as_uint(d2a)) << 32) | (unsigned int)v;
            float dxb = bxx - vx, dyb = bxy - vy, dzb = bxz - vz;
            float d2b = ((dxb * dxb) + (dyb * dyb)) + (dzb * dzb);
            kB = (((unsigned long long)__float_as_uint(d2b)) << 32) | (unsigned int)v;
        }
        la[i] = kA;
        lb[i] = kB;
    }

    // ---------------- phase 1b: Batcher 8-sort network (A/B interleaved) --
    {
        unsigned long long t;
#define CS2(i, j)                                                     \
        if (la[j] < la[i]) { t = la[i]; la[i] = la[j]; la[j] = t; }   \
        if (lb[j] < lb[i]) { t = lb[i]; lb[i] = lb[j]; lb[j] = t; }
        // sort pairs
        CS2(0, 1) CS2(2, 3) CS2(4, 5) CS2(6, 7)
        // merge 2->4
        CS2(0, 2) CS2(1, 3) CS2(4, 6) CS2(5, 7)
        CS2(1, 2) CS2(5, 6)
        // merge 4->8
        CS2(0, 4) CS2(1, 5) CS2(2, 6) CS2(3, 7)
        CS2(2, 4) CS2(3, 5)
        CS2(1, 2) CS2(3, 4) CS2(5, 6)
#undef CS2
    }

    // ---------------- phase 1c: conditional sorted-insert (verbatim) ------
    for (int v = tid + 8 * 512; v < V; v += 512) {
        float vx = verts[v * 3 + 0];
        float vy = verts[v * 3 + 1];
        float vz = verts[v * 3 + 2];

        float dxa = axx - vx, dya = axy - vy, dza = axz - vz;
        float d2a = ((dxa * dxa) + (dya * dya)) + (dza * dza);
        unsigned long long kA =
            (((unsigned long long)__float_as_uint(d2a)) << 32) | (unsigned int)v;
        if (kA < la[7]) {
            la[7] = kA;
#pragma unroll
            for (int j = 7; j > 0; --j) {
                if (la[j] < la[j - 1]) {
                    unsigned long long t = la[j];
                    la[j] = la[j - 1];
                    la[j - 1] = t;
                }
            }
        }

        float dxb = bxx - vx, dyb = bxy - vy, dzb = bxz - vz;
        float d2b = ((dxb * dxb) + (dyb * dyb)) + (dzb * dzb);
        unsigned long long kB =
            (((unsigned long long)__float_as_uint(d2b)) << 32) | (unsigned int)v;
        if (kB < lb[7]) {
            lb[7] = kB;
#pragma unroll
            for (int j = 7; j > 0; --j) {
                if (lb[j] < lb[j - 1]) {
                    unsigned long long t = lb[j];
                    lb[j] = lb[j - 1];
                    lb[j - 1] = t;
                }
            }
        }
    }

    // per-wave exact top-8 extraction, A/B interleaved (R36 verbatim)
#pragma unroll
    for (int j = 0; j < 8; ++j) {
        unsigned long long mA = la[0];
        unsigned long long mB = lb[0];
#pragma unroll
        for (int s = 1; s < 64; s <<= 1) {
            unsigned long long oA = __shfl_xor(mA, s, 64);
            if (oA < mA) mA = oA;
            unsigned long long oB = __shfl_xor(mB, s, 64);
            if (oB < mB) mB = oB;
        }
        if (la[0] == mA) {
#pragma unroll
            for (int t = 0; t < 7; ++t) la[t] = la[t + 1];
            la[7] = ~0ULL;
        }
        if (lb[0] == mB) {
#pragma unroll
            for (int t = 0; t < 7; ++t) lb[t] = lb[t + 1];
            lb[7] = ~0ULL;
        }
        if (lane == 0) { candA[wave * 8 + j] = mA; candB[wave * 8 + j] = mB; }
    }
    __syncthreads();

    // wave 0 merges A, wave 1 merges B (parallel); results to LDS bc arrays
    if (wave < 2) {
        unsigned long long c0 = (wave == 0) ? candA[lane] : candB[lane];
        unsigned long long sel[8];
#pragma unroll
        for (int j = 0; j < 8; ++j) {
            unsigned long long m = c0;
#pragma unroll
            for (int s = 1; s < 64; s <<= 1) {
                unsigned long long o = __shfl_xor(m, s, 64);
                if (o < m) m = o;
            }
            if (c0 == m) c0 = ~0ULL;
            sel[j] = m;
        }

        if (lane == 0) {
            float xx = (wave == 0) ? axx : bxx;
            float xy = (wave == 0) ? axy : bxy;
            float xz = (wave == 0) ? axz : bxz;

            // lane-0 tail: verbatim (bit-identical arithmetic order)
            float invk[8];
            float nsx = 0.f, nsy = 0.f, nsz = 0.f;
#pragma unroll
            for (int j = 0; j < 8; ++j) {
                int id = (int)(sel[j] & 0xffffffffu);
                float d2 = __uint_as_float((unsigned int)(sel[j] >> 32));
                float inv = 1.0f / fmaxf(d2, EPSF);
                invk[j] = inv;
                nsx = nsx + vnorm[id * 3 + 0] * inv;
                nsy = nsy + vnorm[id * 3 + 1] * inv;
                nsz = nsz + vnorm[id * 3 + 2] * inv;
            }
            float Wsum = ((invk[0] + invk[1]) + (invk[2] + invk[3])) +
                         ((invk[4] + invk[5]) + (invk[6] + invk[7]));

            int id0 = (int)(sel[0] & 0xffffffffu);
            float v1x = verts[id0 * 3 + 0];
            float v1y = verts[id0 * 3 + 1];
            float v1z = verts[id0 * 3 + 2];

            float dxv = xx - v1x, dyv = xy - v1y, dzv = xz - v1z;
            float d2v1 = fmaxf(((dxv * dxv) + (dyv * dyv)) + (dzv * dzv), EPSF);
            float den = 0.01f * d2v1;
            float tdx = dxv / den, tdy = dyv / den, tdz = dzv / den;

            float W = Wsum + 100.0f;
            float ntx = (nsx + tdx) / W;
            float nty = (nsy + tdy) / W;
            float ntz = (nsz + tdz) / W;
            float nrm = sqrtf(((ntx * ntx) + (nty * nty)) + (ntz * ntz)) + 1e-8f;

            float fx = v1x - xx, fy = v1y - xy, fz = v1z - xz;
            float fn = sqrtf(((fx * fx) + (fy * fy)) + (fz * fz)) + 1e-8f;

            float* bc = (wave == 0) ? bcA : bcB;
            bc[0] = ntx / nrm; bc[1] = nty / nrm; bc[2] = ntz / nrm;
            bc[3] = v1x; bc[4] = v1y; bc[5] = v1z;
            bc[6] = fx / fn; bc[7] = fy / fn; bc[8] = fz / fn;
        }
    }
    __syncthreads();

    // ---------------- phase 2: ray (R35 verbatim, sources from LDS) -------
    float Ancx = bcA[0], Ancy = bcA[1], Ancz = bcA[2];
    float Adbx = bcA[6], Adby = bcA[7], Adbz = bcA[8];
    float Adax = -Ancx, Aday = -Ancy, Adaz = -Ancz;
    float Bncx = bcB[0], Bncy = bcB[1], Bncz = bcB[2];
    float Bdbx = bcB[6], Bdby = bcB[7], Bdbz = bcB[8];
    float Bdax = -Bncx, Bday = -Bncy, Bdaz = -Bncz;

    const float INF = __uint_as_float(0x7f800000u);

    float tA = INF, tB = INF;
    for (int fi = tid; fi < F; fi += 512) {
        const float4 A4 = *(const float4*)(tri + (size_t)fi * 12);
        const float4 B4 = *(const float4*)(tri + (size_t)fi * 12 + 4);
        const float4 C4 = *(const float4*)(tri + (size_t)fi * 12 + 8);
        tA = mt_test(axx, axy, axz, Adax, Aday, Adaz, A4, B4, C4, tA);
        tB = mt_test(bxx, bxy, bxz, Bdax, Bday, Bdaz, A4, B4, C4, tB);
    }

    {
        unsigned int ma = __float_as_uint(tA);
        unsigned int mb = __float_as_uint(tB);
#pragma unroll
        for (int s = 1; s < 64; s <<= 1) {
            unsigned int oa = __shfl_xor(ma, s, 64);
            if (oa < ma) ma = oa;
            unsigned int ob = __shfl_xor(mb, s, 64);
            if (ob < mb) mb = ob;
        }
        if (lane == 0) { redA[wave] = ma; redB[wave] = mb; }
    }
    __syncthreads();
    if (tid == 0) {
        unsigned int u1A = min(min(min(redA[0], redA[1]), min(redA[2], redA[3])),
                               min(min(redA[4], redA[5]), min(redA[6], redA[7])));
        unsigned int u1B = min(min(min(redB[0], redB[1]), min(redB[2], redB[3])),
                               min(min(redB[4], redB[5]), min(redB[6], redB[7])));
        u1As = u1A; u1Bs = u1B;
        hAf = (u1A < 0x7f800000u) ? 1u : 0u;
        hBf = (u1B < 0x7f800000u) ? 1u : 0u;
    }
    __syncthreads();

    bool needA = (hAf == 0u);                 // block-uniform
    bool needB = hasB && (hBf == 0u);         // block-uniform
    if (needA || needB) {
        float sA = INF, sB = INF;
        for (int fi = tid; fi < F; fi += 512) {
            const float4 A4 = *(const float4*)(tri + (size_t)fi * 12);
            const float4 B4 = *(const float4*)(tri + (size_t)fi * 12 + 4);
            const float4 C4 = *(const float4*)(tri + (size_t)fi * 12 + 8);
            if (needA) sA = mt_test(axx, axy, axz, Adbx, Adby, Adbz, A4, B4, C4, sA);
            if (needB) sB = mt_test(bxx, bxy, bxz, Bdbx, Bdby, Bdbz, A4, B4, C4, sB);
        }
        unsigned int ma = __float_as_uint(sA);
        unsigned int mb = __float_as_uint(sB);
#pragma unroll
        for (int s = 1; s < 64; s <<= 1) {
            unsigned int oa = __shfl_xor(ma, s, 64);
            if (oa < ma) ma = oa;
            unsigned int ob = __shfl_xor(mb, s, 64);
            if (ob < mb) mb = ob;
        }
        if (lane == 0) { redA[wave] = ma; redB[wave] = mb; }
        __syncthreads();
        if (tid == 0) {
            u2As = min(min(min(redA[0], redA[1]), min(redA[2], redA[3])),
                       min(min(redA[4], redA[5]), min(redA[6], redA[7])));
            u2Bs = min(min(min(redB[0], redB[1]), min(redB[2], redB[3])),
                       min(min(redB[4], redB[5]), min(redB[6], redB[7])));
        }
    }

    // ---------------- finalize (verbatim per point), thread 0 -------------
    if (tid != 0) return;
    {
        float t1 = __uint_as_float(u1As);
        bool h1 = t1 < INF;
        float t2 = h1 ? INF : __uint_as_float(u2As);
        bool h2 = t2 < INF;
        float xcx, xcy, xcz;
        if (h1) {
            xcx = axx + ((-Ancx) * t1);
            xcy = axy + ((-Ancy) * t1);
            xcz = axz + ((-Ancz) * t1);
        } else if (h2) {
            xcx = axx + (Adbx * t2);
            xcy = axy + (Adby * t2);
            xcz = axz + (Adbz * t2);
        } else {
            xcx = bcA[3]; xcy = bcA[4]; xcz = bcA[5];
        }
        float s = (((axx - xcx) * Ancx) + ((axy - xcy) * Ancy)) + ((axz - xcz) * Ancz);
        out[pA * 3 + 0] = xcx;
        out[pA * 3 + 1] = xcy;
        out[pA * 3 + 2] = xcz;
        out[3 * N + pA] = s;
        out[4 * N + pA * 3 + 0] = Ancx;
        out[4 * N + pA * 3 + 1] = Ancy;
        out[4 * N + pA * 3 + 2] = Ancz;
    }
    if (hasB) {
        float t1 = __uint_as_float(u1Bs);
        bool h1 = t1 < INF;
        float t2 = h1 ? INF : __uint_as_float(u2Bs);
        bool h2 = t2 < INF;
        float xcx, xcy, xcz;
        if (h1) {
            xcx = bxx + ((-Bncx) * t1);
            xcy = bxy + ((-Bncy) * t1);
            xcz = bxz + ((-Bncz) * t1);
        } else if (h2) {
            xcx = bxx + (Bdbx * t2);
            xcy = bxy + (Bdby * t2);
            xcz = bxz + (Bdbz * t2);
        } else {
            xcx = bcB[3]; xcy = bcB[4]; xcz = bcB[5];
        }
        float s = (((bxx - xcx) * Bncx) + ((bxy - xcy) * Bncy)) + ((bxz - xcz) * Bncz);
        out[pB * 3 + 0] = xcx;
        out[pB * 3 + 1] = xcy;
        out[pB * 3 + 2] = xcz;
        out[3 * N + pB] = s;
        out[4 * N + pB * 3 + 0] = Bncx;
        out[4 * N + pB * 3 + 1] = Bncy;
        out[4 * N + pB * 3 + 2] = Bncz;
    }
}

// ---------------------------------------------------------------------------
extern "C" void kernel_launch(void* const* d_in, const int* in_sizes, int n_in,
                              void* d_out, int out_size, void* d_ws, size_t ws_size,
                              hipStream_t stream) {
    const float* x     = (const float*)d_in[0];
    const float* verts = (const float*)d_in[1];
    const float* vnorm = (const float*)d_in[2];
    const int*   faces = (const int*)d_in[3];
    int N = in_sizes[0] / 3;
    int V = in_sizes[1] / 3;
    int F = in_sizes[3] / 3;

    float* tri = (float*)d_ws;   // F*12 floats (16B-aligned AoS)

    int tblocks = (F + 511) / 512;
    hipLaunchKernelGGL(tri_prep_kernel, dim3(tblocks), dim3(512), 0, stream,
                       verts, faces, tri, F);
    int pblocks = (N + 1) / 2;
    hipLaunchKernelGGL(fused_kernel, dim3(pblocks), dim3(512), 0, stream,
                       x, verts, vnorm, tri, (float*)d_out, N, V, F);
}